// Round 27
// baseline (229.387 us; speedup 1.0000x reference)
//
#include <hip/hip_runtime.h>

#define N_NODES 8000
#define FEAT 64
#define HID 128
#define LOOKBACK 12
#define CAP 64

// ---------------- front kernel: zero cnt + weight stacking + init encoder ----------------
__global__ __launch_bounds__(256)
void front_kernel(int* __restrict__ cnt,
                  const float* __restrict__ x,
                  const float* __restrict__ We1, const float* __restrict__ be1,
                  const float* __restrict__ We2, const float* __restrict__ be2,
                  float* __restrict__ out0,
                  const float* __restrict__ Wl1, const float* __restrict__ Wr1,
                  const float* __restrict__ Wl2, const float* __restrict__ Wr2,
                  float* __restrict__ Ws1, float* __restrict__ Wc2) {
    __shared__ float sW1T[HID * LOOKBACK];   // [h][l]
    __shared__ float sB1[HID];
    __shared__ float sW2[HID];
    const int tid = threadIdx.x;
    if (tid < 16) cnt[blockIdx.x * 16 + tid] = 0;
    {   // stack weights: first 2*16384 threads write one elem each
        const int gid = blockIdx.x * 256 + tid;
        if (gid < 128 * 128) {              // Ws1[k][j] = [Wl1;Wr1] row-stacked
            int k = gid >> 7, j = gid & 127;
            Ws1[gid] = (k < 64) ? Wl1[k * 128 + j] : Wr1[(k - 64) * 128 + j];
        } else if (gid < 2 * 128 * 128) {   // Wc2[k][j] = [Wl2 | Wr2] col-stacked
            int w = gid - 128 * 128;
            int k = w >> 7, j = w & 127;
            Wc2[w] = (j < 64) ? Wl2[k * 64 + j] : Wr2[k * 64 + (j - 64)];
        }
    }
    for (int e = tid; e < HID * LOOKBACK; e += 256) {
        int l = e / HID, h = e % HID;
        sW1T[h * LOOKBACK + l] = We1[e];
    }
    for (int e = tid; e < HID; e += 256) { sB1[e] = be1[e]; sW2[e] = We2[e]; }
    __syncthreads();
    int g = (blockIdx.x * 256 + tid) * 4;    // 500*256*4 == N*F exactly
    float xv[4][LOOKBACK];
    #pragma unroll
    for (int l = 0; l < LOOKBACK; ++l) {
        float4 v = *reinterpret_cast<const float4*>(x + (long)l * N_NODES * FEAT + g);
        xv[0][l] = v.x; xv[1][l] = v.y; xv[2][l] = v.z; xv[3][l] = v.w;
    }
    float b2 = be2[0];
    float acc[4] = {b2, b2, b2, b2};
    for (int h = 0; h < HID; ++h) {
        float s0 = sB1[h], s1 = s0, s2 = s0, s3 = s0;
        #pragma unroll
        for (int l = 0; l < LOOKBACK; ++l) {
            float w = sW1T[h * LOOKBACK + l];
            s0 += xv[0][l] * w; s1 += xv[1][l] * w;
            s2 += xv[2][l] * w; s3 += xv[3][l] * w;
        }
        float w2 = sW2[h];
        acc[0] += fmaxf(s0, 0.0f) * w2; acc[1] += fmaxf(s1, 0.0f) * w2;
        acc[2] += fmaxf(s2, 0.0f) * w2; acc[3] += fmaxf(s3, 0.0f) * w2;
    }
    float4 o = {acc[0], acc[1], acc[2], acc[3]};
    *reinterpret_cast<float4*>(out0 + g) = o;
}

// ---------------- adjacency extraction: stream-then-drain (R18/R19-verified, ~47us) ----
__global__ __launch_bounds__(256)
void build_adj_kernel(const float* __restrict__ adj, int* __restrict__ cnt,
                      int* __restrict__ lists) {
    const long NQ = (long)N_NODES * N_NODES / 4;     // 16,000,000 float4s
    const long STRIDE = 2048L * 256;                 // 524,288 threads
    const long t = (long)blockIdx.x * 256 + threadIdx.x;

    int lc = 0;
    int e0 = 0, e1 = 0, e2 = 0, e3 = 0, e4 = 0;
    int e5 = 0, e6 = 0, e7 = 0, e8 = 0, e9 = 0;

    #pragma unroll 1
    for (long q = t; q < NQ; q += STRIDE) {
        float4 w = *reinterpret_cast<const float4*>(adj + 4 * q);
        if (w.x != 0.0f || w.y != 0.0f || w.z != 0.0f || w.w != 0.0f) {
            float wv[4] = {w.x, w.y, w.z, w.w};
            #pragma unroll
            for (int c = 0; c < 4; ++c) {
                if (wv[c] != 0.0f) {
                    int e = (int)(q * 4 + c);        // linear elem idx = i*8000+j
                    if      (lc == 0) e0 = e;
                    else if (lc == 1) e1 = e;
                    else if (lc == 2) e2 = e;
                    else if (lc == 3) e3 = e;
                    else if (lc == 4) e4 = e;
                    else if (lc == 5) e5 = e;
                    else if (lc == 6) e6 = e;
                    else if (lc == 7) e7 = e;
                    else if (lc == 8) e8 = e;
                    else if (lc == 9) e9 = e;
                    ++lc;
                }
            }
        }
    }
    #define DRAIN(K, EK)                                                     \
        if (lc > K) {                                                        \
            int ii = (EK) / N_NODES;                                         \
            int jj = (EK) % N_NODES;                                         \
            int p = atomicAdd(&cnt[jj], 1);                                  \
            if (p < CAP) lists[(long)jj * CAP + p] = ii;                     \
        }
    DRAIN(0, e0) DRAIN(1, e1) DRAIN(2, e2) DRAIN(3, e3) DRAIN(4, e4)
    DRAIN(5, e5) DRAIN(6, e6) DRAIN(7, e7) DRAIN(8, e8) DRAIN(9, e9)
    #undef DRAIN
}

// ---------------- fused SAGE1 + proj + selfMLP (+step-0 sort; gather v3) ----------------
// Gather v3 (R25/R26-proven mechanism, chain depth 1): 16 edge-groups per node,
// each thread loads the FULL 64-float row (4 independent float4s) of edges
// e==eg (mod 16); shfl_xor(1,2,4,8) tree over the node's 16 consecutive lanes;
// lane eg writes float4 #eg of aggr and of the h row. GEMM phases R19-verbatim.
__global__ __launch_bounds__(256)
void sageproj_kernel(const float* __restrict__ h,
                     int* __restrict__ lists, int* __restrict__ cnt,
                     float* __restrict__ degf, int do_sort,
                     const float* __restrict__ Ws1, const float* __restrict__ bl1,
                     const float* __restrict__ Wc2, const float* __restrict__ bl2,
                     const float* __restrict__ Wf1, const float* __restrict__ bf1,
                     const float* __restrict__ Wf2, const float* __restrict__ bf2,
                     float* __restrict__ pl, float* __restrict__ q) {
    __shared__ float v[16][132];     // [node][k]: k<64 aggr, k>=64 h row
    __shared__ float rr[16][132];    // r1
    __shared__ float tt[16][132];    // t = relu(h@Wf1+bf1)
    __shared__ float xsl[16][68];    // xs
    __shared__ float wbuf[64 * 128]; // 32 KB weight panel chunk
    const int tid = threadIdx.x;
    const int nb = blockIdx.x * 16;
    if (do_sort) {                   // canonicalize own 16 nodes (R16/R19-proven)
        const int wv = tid >> 6, lane = tid & 63;
        #pragma unroll 1
        for (int r = 0; r < 4; ++r) {
            const int n = nb + wv * 4 + r;
            int m = cnt[n]; if (m > CAP) m = CAP;
            int val = (lane < m) ? lists[(long)n * CAP + lane] : 0x7FFFFFFF;
            #pragma unroll
            for (int k = 2; k <= 64; k <<= 1) {
                #pragma unroll
                for (int j = k >> 1; j > 0; j >>= 1) {
                    int other = __shfl_xor(val, j);
                    bool keepMin = (((lane & j) == 0) == ((lane & k) == 0));
                    int mn = val < other ? val : other;
                    int mx = val < other ? other : val;
                    val = keepMin ? mn : mx;
                }
            }
            lists[(long)n * CAP + lane] = val;
            if (lane == 0) { cnt[n] = m; degf[n] = (float)(m > 0 ? m : 1); }
        }
        __syncthreads();
    }
    {   // gather v3: (node = tid>>4) x (eg = tid&15); chain depth ~1
        const int ln2 = tid >> 4;
        const int eg  = tid & 15;
        const int n2 = nb + ln2;
        const int m = cnt[n2];
        const int* l = lists + (long)n2 * CAP;
        float4 a0 = {0,0,0,0}, a1 = {0,0,0,0}, a2 = {0,0,0,0}, a3 = {0,0,0,0};
        for (int e = eg; e < m; e += 16) {
            const float* p = h + (long)l[e] * FEAT;
            float4 b0 = *reinterpret_cast<const float4*>(p);
            float4 b1 = *reinterpret_cast<const float4*>(p + 16);
            float4 b2 = *reinterpret_cast<const float4*>(p + 32);
            float4 b3 = *reinterpret_cast<const float4*>(p + 48);
            a0.x += b0.x; a0.y += b0.y; a0.z += b0.z; a0.w += b0.w;
            a1.x += b1.x; a1.y += b1.y; a1.z += b1.z; a1.w += b1.w;
            a2.x += b2.x; a2.y += b2.y; a2.z += b2.z; a2.w += b2.w;
            a3.x += b3.x; a3.y += b3.y; a3.z += b3.z; a3.w += b3.w;
        }
        // tree-reduce across the 16 lanes of this node (xor 1,2,4,8 stay in-group)
        #define RED(A)                                                       \
            (A).x += __shfl_xor((A).x, 1); (A).y += __shfl_xor((A).y, 1);    \
            (A).z += __shfl_xor((A).z, 1); (A).w += __shfl_xor((A).w, 1);    \
            (A).x += __shfl_xor((A).x, 2); (A).y += __shfl_xor((A).y, 2);    \
            (A).z += __shfl_xor((A).z, 2); (A).w += __shfl_xor((A).w, 2);    \
            (A).x += __shfl_xor((A).x, 4); (A).y += __shfl_xor((A).y, 4);    \
            (A).z += __shfl_xor((A).z, 4); (A).w += __shfl_xor((A).w, 4);    \
            (A).x += __shfl_xor((A).x, 8); (A).y += __shfl_xor((A).y, 8);    \
            (A).z += __shfl_xor((A).z, 8); (A).w += __shfl_xor((A).w, 8);
        RED(a0) RED(a1) RED(a2) RED(a3)
        #undef RED
        // lane eg owns float4 #eg: quadrant qd = eg>>2, slot = eg&3
        const int qd = eg >> 2, sl = eg & 3;
        float4 sel = (qd == 0) ? a0 : (qd == 1) ? a1 : (qd == 2) ? a2 : a3;
        float4 pick;
        pick.x = (sl == 0) ? sel.x : (sl == 1) ? sel.x : sel.x; // placeholder (overwritten below)
        // select the sl-th float4 within quadrant: quadrant holds floats [qd*16, qd*16+16)
        // sel is the SUM of 4 consecutive floats starting at qd*16 + 0? No: sel holds
        // floats qd*16+0..3 in .x..w only for sl==0 layout; we loaded b at offsets
        // p+qd*16 .. so sel = floats [qd*16, qd*16+4). For sl>0 we need lanes' other
        // registers; instead use the fact that after full reduction ALL lanes hold the
        // same a0..a3 = float4s at offsets 0,16,32,48. Lane eg must write float4 #eg
        // (floats eg*4..eg*4+3) which lives INSIDE quadrant eg>>2 at sub-offset (eg&3).
        // a_{qd} covers floats [qd*16, qd*16+4) only -> need sub-offset loads instead.
        // Correct by construction: load b0..b3 at p + eg4 base below.
        (void)pick;
        // recompute properly: write using per-lane offset within already-reduced regs
        // (a0..a3 are float4s at row offsets 0,16,32,48 — NOT what lane eg needs unless
        // sl==0). To keep it simple and correct, lane eg re-reduces nothing: we instead
        // have each lane write quadrant qd only when sl matches the quadrant layout.
        // Simplest correct mapping: 16 float4s needed; we have 4 reduced float4s at
        // offsets {0,16,32,48}. Lanes 0..3 write those 4; remaining offsets are covered
        // by re-loading? NO — restructure: each thread loads its 4 float4s CONSECUTIVE
        // at p + eg*4 is wrong for reuse. Fallback: lanes 0..3 write offsets 0,16,32,48
        // and lanes 4..15 write nothing; the other 12 float4s are covered by b1..b3
        // of lanes 0..3? They ARE a0..a3 of every lane. So:
        const float inv = 1.0f / degf[n2];
        if (eg < 4) {
            float4 w0 = (eg == 0) ? a0 : (eg == 1) ? a1 : (eg == 2) ? a2 : a3;
            // lane eg writes quadrant eg: floats [eg*16, eg*16+4)
            float4 av = {w0.x * inv, w0.y * inv, w0.z * inv, w0.w * inv};
            *reinterpret_cast<float4*>(&v[ln2][eg * 16]) = av;
        }
        // remaining 12 float4s of the aggregate: quadrant qd, sub-slots 1..3 were never
        // loaded (we loaded only 4 float4s at offsets 0,16,32,48 per edge -> only 16 of
        // 64 floats!). THIS PATH IS INCOMPLETE; see corrected full-row loads below.
    }
    // ---- CORRECTED gather (full row): executed instead of the above partial write ----
    __syncthreads();
    {   // gather v3-full: each thread loads floats [0..64) of its edges in 4 float4s
        const int ln2 = tid >> 4;
        const int eg  = tid & 15;
        const int n2 = nb + ln2;
        const int m = cnt[n2];
        const int* l = lists + (long)n2 * CAP;
        float4 a0 = {0,0,0,0}, a1 = {0,0,0,0}, a2 = {0,0,0,0}, a3 = {0,0,0,0};
        for (int e = eg; e < m; e += 16) {
            const float* p = h + (long)l[e] * FEAT;
            float4 b0 = *reinterpret_cast<const float4*>(p);
            float4 b1 = *reinterpret_cast<const float4*>(p + 4);
            float4 b2 = *reinterpret_cast<const float4*>(p + 8);
            float4 b3 = *reinterpret_cast<const float4*>(p + 12);
            a0.x += b0.x; a0.y += b0.y; a0.z += b0.z; a0.w += b0.w;
            a1.x += b1.x; a1.y += b1.y; a1.z += b1.z; a1.w += b1.w;
            a2.x += b2.x; a2.y += b2.y; a2.z += b2.z; a2.w += b2.w;
            a3.x += b3.x; a3.y += b3.y; a3.z += b3.z; a3.w += b3.w;
        }
        #define RED(A)                                                       \
            (A).x += __shfl_xor((A).x, 1); (A).y += __shfl_xor((A).y, 1);    \
            (A).z += __shfl_xor((A).z, 1); (A).w += __shfl_xor((A).w, 1);    \
            (A).x += __shfl_xor((A).x, 2); (A).y += __shfl_xor((A).y, 2);    \
            (A).z += __shfl_xor((A).z, 2); (A).w += __shfl_xor((A).w, 2);    \
            (A).x += __shfl_xor((A).x, 4); (A).y += __shfl_xor((A).y, 4);    \
            (A).z += __shfl_xor((A).z, 4); (A).w += __shfl_xor((A).w, 4);    \
            (A).x += __shfl_xor((A).x, 8); (A).y += __shfl_xor((A).y, 8);    \
            (A).z += __shfl_xor((A).z, 8); (A).w += __shfl_xor((A).w, 8);
        RED(a0) RED(a1) RED(a2) RED(a3)
        #undef RED
        const float inv = 1.0f / degf[n2];
        if (eg < 4) {          // a0..a3 cover floats [0,16): lanes 0..3 write slots 0..3
            float4 s = (eg == 0) ? a0 : (eg == 1) ? a1 : (eg == 2) ? a2 : a3;
            float4 av = {s.x * inv, s.y * inv, s.z * inv, s.w * inv};
            *reinterpret_cast<float4*>(&v[ln2][eg * 4]) = av;
        }
        // wait: a0..a3 only cover floats [0,16) of the row — the loop above loaded
        // p+0..15 only. Extend: second pass for floats [16,64) handled by eg groups.
        float4 c0 = {0,0,0,0}, c1 = {0,0,0,0}, c2 = {0,0,0,0};
        float4 d0 = {0,0,0,0}, d1 = {0,0,0,0}, d2 = {0,0,0,0};
        float4 e0v = {0,0,0,0}, e1v = {0,0,0,0}, e2v = {0,0,0,0};
        float4 f0v = {0,0,0,0}, f1v = {0,0,0,0}, f2v = {0,0,0,0};
        for (int e = eg; e < m; e += 16) {
            const float* p = h + (long)l[e] * FEAT;
            float4 u0 = *reinterpret_cast<const float4*>(p + 16);
            float4 u1 = *reinterpret_cast<const float4*>(p + 20);
            float4 u2 = *reinterpret_cast<const float4*>(p + 24);
            float4 u3 = *reinterpret_cast<const float4*>(p + 28);
            float4 u4 = *reinterpret_cast<const float4*>(p + 32);
            float4 u5 = *reinterpret_cast<const float4*>(p + 36);
            float4 u6 = *reinterpret_cast<const float4*>(p + 40);
            float4 u7 = *reinterpret_cast<const float4*>(p + 44);
            float4 u8 = *reinterpret_cast<const float4*>(p + 48);
            float4 u9 = *reinterpret_cast<const float4*>(p + 52);
            float4 ua = *reinterpret_cast<const float4*>(p + 56);
            float4 ub = *reinterpret_cast<const float4*>(p + 60);
            c0.x += u0.x; c0.y += u0.y; c0.z += u0.z; c0.w += u0.w;
            c1.x += u1.x; c1.y += u1.y; c1.z += u1.z; c1.w += u1.w;
            c2.x += u2.x; c2.y += u2.y; c2.z += u2.z; c2.w += u2.w;
            d0.x += u3.x; d0.y += u3.y; d0.z += u3.z; d0.w += u3.w;
            d1.x += u4.x; d1.y += u4.y; d1.z += u4.z; d1.w += u4.w;
            d2.x += u5.x; d2.y += u5.y; d2.z += u5.z; d2.w += u5.w;
            e0v.x += u6.x; e0v.y += u6.y; e0v.z += u6.z; e0v.w += u6.w;
            e1v.x += u7.x; e1v.y += u7.y; e1v.z += u7.z; e1v.w += u7.w;
            e2v.x += u8.x; e2v.y += u8.y; e2v.z += u8.z; e2v.w += u8.w;
            f0v.x += u9.x; f0v.y += u9.y; f0v.z += u9.z; f0v.w += u9.w;
            f1v.x += ua.x; f1v.y += ua.y; f1v.z += ua.z; f1v.w += ua.w;
            f2v.x += ub.x; f2v.y += ub.y; f2v.z += ub.z; f2v.w += ub.w;
        }
        #define RED(A)                                                       \
            (A).x += __shfl_xor((A).x, 1); (A).y += __shfl_xor((A).y, 1);    \
            (A).z += __shfl_xor((A).z, 1); (A).w += __shfl_xor((A).w, 1);    \
            (A).x += __shfl_xor((A).x, 2); (A).y += __shfl_xor((A).y, 2);    \
            (A).z += __shfl_xor((A).z, 2); (A).w += __shfl_xor((A).w, 2);    \
            (A).x += __shfl_xor((A).x, 4); (A).y += __shfl_xor((A).y, 4);    \
            (A).z += __shfl_xor((A).z, 4); (A).w += __shfl_xor((A).w, 4);    \
            (A).x += __shfl_xor((A).x, 8); (A).y += __shfl_xor((A).y, 8);    \
            (A).z += __shfl_xor((A).z, 8); (A).w += __shfl_xor((A).w, 8);
        RED(c0) RED(c1) RED(c2) RED(d0) RED(d1) RED(d2)
        RED(e0v) RED(e1v) RED(e2v) RED(f0v) RED(f1v) RED(f2v)
        #undef RED
        if (eg >= 4) {         // lanes 4..15 write float4 slots 4..15
            float4 s;
            switch (eg) {
                case 4:  s = c0;  break;  case 5:  s = c1;  break;
                case 6:  s = c2;  break;  case 7:  s = d0;  break;
                case 8:  s = d1;  break;  case 9:  s = d2;  break;
                case 10: s = e0v; break;  case 11: s = e1v; break;
                case 12: s = e2v; break;  case 13: s = f0v; break;
                case 14: s = f1v; break;  default: s = f2v; break;
            }
            float4 av = {s.x * inv, s.y * inv, s.z * inv, s.w * inv};
            *reinterpret_cast<float4*>(&v[ln2][eg * 4]) = av;
        }
        // h row: lane eg writes float4 #eg
        *reinterpret_cast<float4*>(&v[ln2][64 + eg * 4]) =
            *reinterpret_cast<const float4*>(h + (long)n2 * FEAT + eg * 4);
    }
    const int ln = tid >> 4, jg = tid & 15;
    const int n = nb + ln;
    const int c0 = jg * 4;
    // ---- P1: rr = relu([aggr|h] @ Ws1 + bl1), K=128 in 2 chunks ----
    {
        float4 b0 = *reinterpret_cast<const float4*>(bl1 + c0);
        float4 b1 = *reinterpret_cast<const float4*>(bl1 + 64 + c0);
        float A0[4] = {b0.x, b0.y, b0.z, b0.w};
        float A1[4] = {b1.x, b1.y, b1.z, b1.w};
        for (int kc = 0; kc < 2; ++kc) {
            __syncthreads();                     // prev consumers done / v ready
            for (int e = tid; e < 2048; e += 256)
                *(reinterpret_cast<float4*>(wbuf) + e) =
                    *(reinterpret_cast<const float4*>(Ws1 + kc * 8192) + e);
            __syncthreads();
            #pragma unroll 4
            for (int k = 0; k < 64; ++k) {
                float a = v[ln][kc * 64 + k];
                float4 w0 = *reinterpret_cast<const float4*>(&wbuf[k * 128 + c0]);
                float4 w1 = *reinterpret_cast<const float4*>(&wbuf[k * 128 + 64 + c0]);
                A0[0] += a * w0.x; A0[1] += a * w0.y; A0[2] += a * w0.z; A0[3] += a * w0.w;
                A1[0] += a * w1.x; A1[1] += a * w1.y; A1[2] += a * w1.z; A1[3] += a * w1.w;
            }
        }
        float4 o0 = {fmaxf(A0[0],0.f), fmaxf(A0[1],0.f), fmaxf(A0[2],0.f), fmaxf(A0[3],0.f)};
        float4 o1 = {fmaxf(A1[0],0.f), fmaxf(A1[1],0.f), fmaxf(A1[2],0.f), fmaxf(A1[3],0.f)};
        *reinterpret_cast<float4*>(&rr[ln][c0]) = o0;
        *reinterpret_cast<float4*>(&rr[ln][64 + c0]) = o1;
    }
    // ---- P2: tt = relu(h @ Wf1 + bf1), K=64, one chunk ----
    {
        float4 b0 = *reinterpret_cast<const float4*>(bf1 + c0);
        float4 b1 = *reinterpret_cast<const float4*>(bf1 + 64 + c0);
        float A0[4] = {b0.x, b0.y, b0.z, b0.w};
        float A1[4] = {b1.x, b1.y, b1.z, b1.w};
        __syncthreads();
        for (int e = tid; e < 2048; e += 256)
            *(reinterpret_cast<float4*>(wbuf) + e) =
                *(reinterpret_cast<const float4*>(Wf1) + e);
        __syncthreads();
        #pragma unroll 4
        for (int k = 0; k < 64; ++k) {
            float a = v[ln][64 + k];
            float4 w0 = *reinterpret_cast<const float4*>(&wbuf[k * 128 + c0]);
            float4 w1 = *reinterpret_cast<const float4*>(&wbuf[k * 128 + 64 + c0]);
            A0[0] += a * w0.x; A0[1] += a * w0.y; A0[2] += a * w0.z; A0[3] += a * w0.w;
            A1[0] += a * w1.x; A1[1] += a * w1.y; A1[2] += a * w1.z; A1[3] += a * w1.w;
        }
        float4 o0 = {fmaxf(A0[0],0.f), fmaxf(A0[1],0.f), fmaxf(A0[2],0.f), fmaxf(A0[3],0.f)};
        float4 o1 = {fmaxf(A1[0],0.f), fmaxf(A1[1],0.f), fmaxf(A1[2],0.f), fmaxf(A1[3],0.f)};
        *reinterpret_cast<float4*>(&tt[ln][c0]) = o0;
        *reinterpret_cast<float4*>(&tt[ln][64 + c0]) = o1;
    }
    // ---- P3: xsl = tt @ Wf2 + bf2, K=128, 64 cols (Wf2 = [128][64]) ----
    {
        float4 b0 = *reinterpret_cast<const float4*>(bf2 + c0);
        float X[4] = {b0.x, b0.y, b0.z, b0.w};
        __syncthreads();
        for (int e = tid; e < 2048; e += 256)
            *(reinterpret_cast<float4*>(wbuf) + e) =
                *(reinterpret_cast<const float4*>(Wf2) + e);
        __syncthreads();
        #pragma unroll 4
        for (int k = 0; k < 128; ++k) {
            float a = tt[ln][k];
            float4 w = *reinterpret_cast<const float4*>(&wbuf[k * 64 + c0]);
            X[0] += a * w.x; X[1] += a * w.y; X[2] += a * w.z; X[3] += a * w.w;
        }
        float4 o = {X[0], X[1], X[2], X[3]};
        *reinterpret_cast<float4*>(&xsl[ln][c0]) = o;
    }
    // ---- P4: [pl|q] = rr @ Wc2 (+ bl2 + xsl on q half), K=128 in 2 chunks ----
    {
        float P0[4] = {0, 0, 0, 0};
        float P1[4] = {0, 0, 0, 0};
        for (int kc = 0; kc < 2; ++kc) {
            __syncthreads();
            for (int e = tid; e < 2048; e += 256)
                *(reinterpret_cast<float4*>(wbuf) + e) =
                    *(reinterpret_cast<const float4*>(Wc2 + kc * 8192) + e);
            __syncthreads();
            #pragma unroll 4
            for (int k = 0; k < 64; ++k) {
                float a = rr[ln][kc * 64 + k];
                float4 w0 = *reinterpret_cast<const float4*>(&wbuf[k * 128 + c0]);
                float4 w1 = *reinterpret_cast<const float4*>(&wbuf[k * 128 + 64 + c0]);
                P0[0] += a * w0.x; P0[1] += a * w0.y; P0[2] += a * w0.z; P0[3] += a * w0.w;
                P1[0] += a * w1.x; P1[1] += a * w1.y; P1[2] += a * w1.z; P1[3] += a * w1.w;
            }
        }
        float4 op = {P0[0], P0[1], P0[2], P0[3]};
        *reinterpret_cast<float4*>(pl + (long)n * FEAT + c0) = op;
        float4 bv = *reinterpret_cast<const float4*>(bl2 + c0);
        float4 oq = {P1[0] + bv.x + xsl[ln][c0 + 0],
                     P1[1] + bv.y + xsl[ln][c0 + 1],
                     P1[2] + bv.z + xsl[ln][c0 + 2],
                     P1[3] + bv.w + xsl[ln][c0 + 3]};
        *reinterpret_cast<float4*>(q + (long)n * FEAT + c0) = oq;
    }
}

// ---------------- gather + Euler epilogue v3 (R26 verbatim) ----------------
__global__ __launch_bounds__(256)
void epi_kernel(const float* __restrict__ pl, const float* __restrict__ q,
                const int* __restrict__ lists, const int* __restrict__ cnt,
                const float* __restrict__ degf, const float* __restrict__ hcur,
                const float* __restrict__ tspan, int step,
                float* __restrict__ hnext) {
    const int tid  = threadIdx.x;
    const int nw   = tid >> 6;            // node within block (one wave per node)
    const int lane = tid & 63;
    const int n  = blockIdx.x * 4 + nw;
    const int eg = lane >> 2;             // neighbor group 0..15
    const int fq = lane & 3;              // feature quad 0..3 (4 float4s each)
    const int m  = cnt[n];
    const int* l = lists + (long)n * CAP;
    float4 a0 = {0,0,0,0}, a1 = {0,0,0,0}, a2 = {0,0,0,0}, a3 = {0,0,0,0};
    for (int e = eg; e < m; e += 16) {
        const float* p = pl + (long)l[e] * FEAT + fq * 16;
        float4 b0 = *reinterpret_cast<const float4*>(p);
        float4 b1 = *reinterpret_cast<const float4*>(p + 4);
        float4 b2 = *reinterpret_cast<const float4*>(p + 8);
        float4 b3 = *reinterpret_cast<const float4*>(p + 12);
        a0.x += b0.x; a0.y += b0.y; a0.z += b0.z; a0.w += b0.w;
        a1.x += b1.x; a1.y += b1.y; a1.z += b1.z; a1.w += b1.w;
        a2.x += b2.x; a2.y += b2.y; a2.z += b2.z; a2.w += b2.w;
        a3.x += b3.x; a3.y += b3.y; a3.z += b3.z; a3.w += b3.w;
    }
    #define RED(A)                                                           \
        (A).x += __shfl_xor((A).x, 4);  (A).y += __shfl_xor((A).y, 4);       \
        (A).z += __shfl_xor((A).z, 4);  (A).w += __shfl_xor((A).w, 4);       \
        (A).x += __shfl_xor((A).x, 8);  (A).y += __shfl_xor((A).y, 8);       \
        (A).z += __shfl_xor((A).z, 8);  (A).w += __shfl_xor((A).w, 8);       \
        (A).x += __shfl_xor((A).x, 16); (A).y += __shfl_xor((A).y, 16);      \
        (A).z += __shfl_xor((A).z, 16); (A).w += __shfl_xor((A).w, 16);      \
        (A).x += __shfl_xor((A).x, 32); (A).y += __shfl_xor((A).y, 32);      \
        (A).z += __shfl_xor((A).z, 32); (A).w += __shfl_xor((A).w, 32);
    RED(a0) RED(a1) RED(a2) RED(a3)
    #undef RED
    if (eg < 4) {                         // writer: float4 idx fq*4 + eg
        float4 a = (eg == 0) ? a0 : (eg == 1) ? a1 : (eg == 2) ? a2 : a3;
        const int f0 = (fq * 4 + eg) * 4;
        const float inv = 1.0f / degf[n];
        const float dt = tspan[step + 1] - tspan[step];
        float4 qv = *reinterpret_cast<const float4*>(q + (long)n * FEAT + f0);
        float4 hv = *reinterpret_cast<const float4*>(hcur + (long)n * FEAT + f0);
        float s0 = qv.x + a.x * inv, s1 = qv.y + a.y * inv;
        float s2 = qv.z + a.z * inv, s3 = qv.w + a.w * inv;
        s0 = fminf(fmaxf(s0, -1000.f), 1000.f); s1 = fminf(fmaxf(s1, -1000.f), 1000.f);
        s2 = fminf(fmaxf(s2, -1000.f), 1000.f); s3 = fminf(fmaxf(s3, -1000.f), 1000.f);
        float4 o = {hv.x + dt * s0, hv.y + dt * s1, hv.z + dt * s2, hv.w + dt * s3};
        *reinterpret_cast<float4*>(hnext + (long)n * FEAT + f0) = o;
    }
}

extern "C" void kernel_launch(void* const* d_in, const int* in_sizes, int n_in,
                              void* d_out, int out_size, void* d_ws, size_t ws_size,
                              hipStream_t stream) {
    const float* tspan = (const float*)d_in[0];
    const float* x     = (const float*)d_in[1];
    const float* adj   = (const float*)d_in[2];
    const float* We1   = (const float*)d_in[3];
    const float* be1   = (const float*)d_in[4];
    const float* We2   = (const float*)d_in[5];
    const float* be2   = (const float*)d_in[6];
    const float* Wf1   = (const float*)d_in[7];
    const float* bf1   = (const float*)d_in[8];
    const float* Wf2   = (const float*)d_in[9];
    const float* bf2   = (const float*)d_in[10];
    const float* Wl1   = (const float*)d_in[11];
    const float* bl1   = (const float*)d_in[12];
    const float* Wr1   = (const float*)d_in[13];
    const float* Wl2   = (const float*)d_in[14];
    const float* bl2   = (const float*)d_in[15];
    const float* Wr2   = (const float*)d_in[16];
    float* out = (float*)d_out;

    // workspace layout (bytes)
    char* ws = (char*)d_ws;
    int*   lists = (int*)  (ws + 0);           // 8000*64*4  = 2,048,000
    int*   cnt   = (int*)  (ws + 2048000);     // 32,000
    float* degf  = (float*)(ws + 2080000);     // 32,000
    float* Ws1   = (float*)(ws + 2112000);     // 65,536
    float* Wc2   = (float*)(ws + 2177536);     // 65,536
    float* pl    = (float*)(ws + 2243072);     // 2,048,000
    float* q     = (float*)(ws + 4291072);     // 2,048,000
    // total 6,339,072 bytes

    front_kernel<<<500, 256, 0, stream>>>(cnt, x, We1, be1, We2, be2, out,
                                          Wl1, Wr1, Wl2, Wr2, Ws1, Wc2);
    build_adj_kernel<<<2048, 256, 0, stream>>>(adj, cnt, lists);

    for (int s = 0; s < 3; ++s) {
        const float* hcur  = out + (long)s       * N_NODES * FEAT;
        float*       hnext = out + (long)(s + 1) * N_NODES * FEAT;
        sageproj_kernel<<<500, 256, 0, stream>>>(hcur, lists, cnt, degf, (s == 0) ? 1 : 0,
                                                 Ws1, bl1, Wc2, bl2,
                                                 Wf1, bf1, Wf2, bf2, pl, q);
        epi_kernel<<<2000, 256, 0, stream>>>(pl, q, lists, cnt, degf, hcur, tspan, s, hnext);
    }
}

// Round 28
// 214.659 us; speedup vs baseline: 1.0686x; 1.0686x over previous
//
#include <hip/hip_runtime.h>

#define N_NODES 8000
#define FEAT 64
#define HID 128
#define LOOKBACK 12
#define CAP 64

// ---------------- front kernel: zero cnt + weight stacking + init encoder ----------------
__global__ __launch_bounds__(256)
void front_kernel(int* __restrict__ cnt,
                  const float* __restrict__ x,
                  const float* __restrict__ We1, const float* __restrict__ be1,
                  const float* __restrict__ We2, const float* __restrict__ be2,
                  float* __restrict__ out0,
                  const float* __restrict__ Wl1, const float* __restrict__ Wr1,
                  const float* __restrict__ Wl2, const float* __restrict__ Wr2,
                  float* __restrict__ Ws1, float* __restrict__ Wc2) {
    __shared__ float sW1T[HID * LOOKBACK];   // [h][l]
    __shared__ float sB1[HID];
    __shared__ float sW2[HID];
    const int tid = threadIdx.x;
    if (tid < 16) cnt[blockIdx.x * 16 + tid] = 0;
    {   // stack weights: first 2*16384 threads write one elem each
        const int gid = blockIdx.x * 256 + tid;
        if (gid < 128 * 128) {              // Ws1[k][j] = [Wl1;Wr1] row-stacked
            int k = gid >> 7, j = gid & 127;
            Ws1[gid] = (k < 64) ? Wl1[k * 128 + j] : Wr1[(k - 64) * 128 + j];
        } else if (gid < 2 * 128 * 128) {   // Wc2[k][j] = [Wl2 | Wr2] col-stacked
            int w = gid - 128 * 128;
            int k = w >> 7, j = w & 127;
            Wc2[w] = (j < 64) ? Wl2[k * 64 + j] : Wr2[k * 64 + (j - 64)];
        }
    }
    for (int e = tid; e < HID * LOOKBACK; e += 256) {
        int l = e / HID, h = e % HID;
        sW1T[h * LOOKBACK + l] = We1[e];
    }
    for (int e = tid; e < HID; e += 256) { sB1[e] = be1[e]; sW2[e] = We2[e]; }
    __syncthreads();
    int g = (blockIdx.x * 256 + tid) * 4;    // 500*256*4 == N*F exactly
    float xv[4][LOOKBACK];
    #pragma unroll
    for (int l = 0; l < LOOKBACK; ++l) {
        float4 v = *reinterpret_cast<const float4*>(x + (long)l * N_NODES * FEAT + g);
        xv[0][l] = v.x; xv[1][l] = v.y; xv[2][l] = v.z; xv[3][l] = v.w;
    }
    float b2 = be2[0];
    float acc[4] = {b2, b2, b2, b2};
    for (int h = 0; h < HID; ++h) {
        float s0 = sB1[h], s1 = s0, s2 = s0, s3 = s0;
        #pragma unroll
        for (int l = 0; l < LOOKBACK; ++l) {
            float w = sW1T[h * LOOKBACK + l];
            s0 += xv[0][l] * w; s1 += xv[1][l] * w;
            s2 += xv[2][l] * w; s3 += xv[3][l] * w;
        }
        float w2 = sW2[h];
        acc[0] += fmaxf(s0, 0.0f) * w2; acc[1] += fmaxf(s1, 0.0f) * w2;
        acc[2] += fmaxf(s2, 0.0f) * w2; acc[3] += fmaxf(s3, 0.0f) * w2;
    }
    float4 o = {acc[0], acc[1], acc[2], acc[3]};
    *reinterpret_cast<float4*>(out0 + g) = o;
}

// ---------------- adjacency extraction: stream-then-drain (R18/R19-verified, ~47us) ----
__global__ __launch_bounds__(256)
void build_adj_kernel(const float* __restrict__ adj, int* __restrict__ cnt,
                      int* __restrict__ lists) {
    const long NQ = (long)N_NODES * N_NODES / 4;     // 16,000,000 float4s
    const long STRIDE = 2048L * 256;                 // 524,288 threads
    const long t = (long)blockIdx.x * 256 + threadIdx.x;

    int lc = 0;
    int e0 = 0, e1 = 0, e2 = 0, e3 = 0, e4 = 0;
    int e5 = 0, e6 = 0, e7 = 0, e8 = 0, e9 = 0;

    #pragma unroll 1
    for (long q = t; q < NQ; q += STRIDE) {
        float4 w = *reinterpret_cast<const float4*>(adj + 4 * q);
        if (w.x != 0.0f || w.y != 0.0f || w.z != 0.0f || w.w != 0.0f) {
            float wv[4] = {w.x, w.y, w.z, w.w};
            #pragma unroll
            for (int c = 0; c < 4; ++c) {
                if (wv[c] != 0.0f) {
                    int e = (int)(q * 4 + c);        // linear elem idx = i*8000+j
                    if      (lc == 0) e0 = e;
                    else if (lc == 1) e1 = e;
                    else if (lc == 2) e2 = e;
                    else if (lc == 3) e3 = e;
                    else if (lc == 4) e4 = e;
                    else if (lc == 5) e5 = e;
                    else if (lc == 6) e6 = e;
                    else if (lc == 7) e7 = e;
                    else if (lc == 8) e8 = e;
                    else if (lc == 9) e9 = e;
                    ++lc;
                }
            }
        }
    }
    #define DRAIN(K, EK)                                                     \
        if (lc > K) {                                                        \
            int ii = (EK) / N_NODES;                                         \
            int jj = (EK) % N_NODES;                                         \
            int p = atomicAdd(&cnt[jj], 1);                                  \
            if (p < CAP) lists[(long)jj * CAP + p] = ii;                     \
        }
    DRAIN(0, e0) DRAIN(1, e1) DRAIN(2, e2) DRAIN(3, e3) DRAIN(4, e4)
    DRAIN(5, e5) DRAIN(6, e6) DRAIN(7, e7) DRAIN(8, e8) DRAIN(9, e9)
    #undef DRAIN
}

// ---------------- fused SAGE1 + proj + selfMLP (+step-0 sort; gather v2.5) ----------------
// Gather v2.5 (R25/R26-proven latency mechanism): node's 16 threads split as
// 8 edge-groups x 2 feature-halves. Thread (eg,fh) sums edges e==eg (mod 8),
// loading its 32-float half-row as 8 independent float4s (chain depth 2 at
// mean m=16). shfl_xor(2,4,8) reduces across eg (lane bits 1-3, wave-local,
// fh preserved). Lane (eg,fh) writes aggr float4 slot fh*8+eg; h-row slot sub.
// GEMM phases R19-verbatim.
__global__ __launch_bounds__(256)
void sageproj_kernel(const float* __restrict__ h,
                     int* __restrict__ lists, int* __restrict__ cnt,
                     float* __restrict__ degf, int do_sort,
                     const float* __restrict__ Ws1, const float* __restrict__ bl1,
                     const float* __restrict__ Wc2, const float* __restrict__ bl2,
                     const float* __restrict__ Wf1, const float* __restrict__ bf1,
                     const float* __restrict__ Wf2, const float* __restrict__ bf2,
                     float* __restrict__ pl, float* __restrict__ q) {
    __shared__ float v[16][132];     // [node][k]: k<64 aggr, k>=64 h row
    __shared__ float rr[16][132];    // r1
    __shared__ float tt[16][132];    // t = relu(h@Wf1+bf1)
    __shared__ float xsl[16][68];    // xs
    __shared__ float wbuf[64 * 128]; // 32 KB weight panel chunk
    const int tid = threadIdx.x;
    const int nb = blockIdx.x * 16;
    if (do_sort) {                   // canonicalize own 16 nodes (R16/R19-proven)
        const int wv = tid >> 6, lane = tid & 63;
        #pragma unroll 1
        for (int r = 0; r < 4; ++r) {
            const int n = nb + wv * 4 + r;
            int m = cnt[n]; if (m > CAP) m = CAP;
            int val = (lane < m) ? lists[(long)n * CAP + lane] : 0x7FFFFFFF;
            #pragma unroll
            for (int k = 2; k <= 64; k <<= 1) {
                #pragma unroll
                for (int j = k >> 1; j > 0; j >>= 1) {
                    int other = __shfl_xor(val, j);
                    bool keepMin = (((lane & j) == 0) == ((lane & k) == 0));
                    int mn = val < other ? val : other;
                    int mx = val < other ? other : val;
                    val = keepMin ? mn : mx;
                }
            }
            lists[(long)n * CAP + lane] = val;
            if (lane == 0) { cnt[n] = m; degf[n] = (float)(m > 0 ? m : 1); }
        }
        __syncthreads();
    }
    {   // gather v2.5: (node = tid>>4) x (eg = (tid>>1)&7) x (fh = tid&1)
        const int ln2 = tid >> 4;
        const int sub = tid & 15;
        const int eg  = sub >> 1;
        const int fh  = sub & 1;
        const int n2 = nb + ln2;
        const int m = cnt[n2];
        const int* l = lists + (long)n2 * CAP;
        float4 a0 = {0,0,0,0}, a1 = {0,0,0,0}, a2 = {0,0,0,0}, a3 = {0,0,0,0};
        float4 a4 = {0,0,0,0}, a5 = {0,0,0,0}, a6 = {0,0,0,0}, a7 = {0,0,0,0};
        for (int e = eg; e < m; e += 8) {
            const float* p = h + (long)l[e] * FEAT + fh * 32;
            float4 b0 = *reinterpret_cast<const float4*>(p);
            float4 b1 = *reinterpret_cast<const float4*>(p + 4);
            float4 b2 = *reinterpret_cast<const float4*>(p + 8);
            float4 b3 = *reinterpret_cast<const float4*>(p + 12);
            float4 b4 = *reinterpret_cast<const float4*>(p + 16);
            float4 b5 = *reinterpret_cast<const float4*>(p + 20);
            float4 b6 = *reinterpret_cast<const float4*>(p + 24);
            float4 b7 = *reinterpret_cast<const float4*>(p + 28);
            a0.x += b0.x; a0.y += b0.y; a0.z += b0.z; a0.w += b0.w;
            a1.x += b1.x; a1.y += b1.y; a1.z += b1.z; a1.w += b1.w;
            a2.x += b2.x; a2.y += b2.y; a2.z += b2.z; a2.w += b2.w;
            a3.x += b3.x; a3.y += b3.y; a3.z += b3.z; a3.w += b3.w;
            a4.x += b4.x; a4.y += b4.y; a4.z += b4.z; a4.w += b4.w;
            a5.x += b5.x; a5.y += b5.y; a5.z += b5.z; a5.w += b5.w;
            a6.x += b6.x; a6.y += b6.y; a6.z += b6.z; a6.w += b6.w;
            a7.x += b7.x; a7.y += b7.y; a7.z += b7.z; a7.w += b7.w;
        }
        // reduce across eg: lane bits 1-3 (stays within node group, preserves fh)
        #define RED(A)                                                       \
            (A).x += __shfl_xor((A).x, 2); (A).y += __shfl_xor((A).y, 2);    \
            (A).z += __shfl_xor((A).z, 2); (A).w += __shfl_xor((A).w, 2);    \
            (A).x += __shfl_xor((A).x, 4); (A).y += __shfl_xor((A).y, 4);    \
            (A).z += __shfl_xor((A).z, 4); (A).w += __shfl_xor((A).w, 4);    \
            (A).x += __shfl_xor((A).x, 8); (A).y += __shfl_xor((A).y, 8);    \
            (A).z += __shfl_xor((A).z, 8); (A).w += __shfl_xor((A).w, 8);
        RED(a0) RED(a1) RED(a2) RED(a3) RED(a4) RED(a5) RED(a6) RED(a7)
        #undef RED
        const float inv = 1.0f / degf[n2];
        // lane (eg,fh) writes aggr float4 slot fh*8 + eg (value a_{eg} of half fh)
        float4 s;
        switch (eg) {
            case 0: s = a0; break;  case 1: s = a1; break;
            case 2: s = a2; break;  case 3: s = a3; break;
            case 4: s = a4; break;  case 5: s = a5; break;
            case 6: s = a6; break;  default: s = a7; break;
        }
        float4 av = {s.x * inv, s.y * inv, s.z * inv, s.w * inv};
        *reinterpret_cast<float4*>(&v[ln2][(fh * 8 + eg) * 4]) = av;
        // h row: lane sub writes float4 #sub
        *reinterpret_cast<float4*>(&v[ln2][64 + sub * 4]) =
            *reinterpret_cast<const float4*>(h + (long)n2 * FEAT + sub * 4);
    }
    const int ln = tid >> 4, jg = tid & 15;
    const int n = nb + ln;
    const int c0 = jg * 4;
    // ---- P1: rr = relu([aggr|h] @ Ws1 + bl1), K=128 in 2 chunks ----
    {
        float4 b0 = *reinterpret_cast<const float4*>(bl1 + c0);
        float4 b1 = *reinterpret_cast<const float4*>(bl1 + 64 + c0);
        float A0[4] = {b0.x, b0.y, b0.z, b0.w};
        float A1[4] = {b1.x, b1.y, b1.z, b1.w};
        for (int kc = 0; kc < 2; ++kc) {
            __syncthreads();                     // prev consumers done / v ready
            for (int e = tid; e < 2048; e += 256)
                *(reinterpret_cast<float4*>(wbuf) + e) =
                    *(reinterpret_cast<const float4*>(Ws1 + kc * 8192) + e);
            __syncthreads();
            #pragma unroll 4
            for (int k = 0; k < 64; ++k) {
                float a = v[ln][kc * 64 + k];
                float4 w0 = *reinterpret_cast<const float4*>(&wbuf[k * 128 + c0]);
                float4 w1 = *reinterpret_cast<const float4*>(&wbuf[k * 128 + 64 + c0]);
                A0[0] += a * w0.x; A0[1] += a * w0.y; A0[2] += a * w0.z; A0[3] += a * w0.w;
                A1[0] += a * w1.x; A1[1] += a * w1.y; A1[2] += a * w1.z; A1[3] += a * w1.w;
            }
        }
        float4 o0 = {fmaxf(A0[0],0.f), fmaxf(A0[1],0.f), fmaxf(A0[2],0.f), fmaxf(A0[3],0.f)};
        float4 o1 = {fmaxf(A1[0],0.f), fmaxf(A1[1],0.f), fmaxf(A1[2],0.f), fmaxf(A1[3],0.f)};
        *reinterpret_cast<float4*>(&rr[ln][c0]) = o0;
        *reinterpret_cast<float4*>(&rr[ln][64 + c0]) = o1;
    }
    // ---- P2: tt = relu(h @ Wf1 + bf1), K=64, one chunk ----
    {
        float4 b0 = *reinterpret_cast<const float4*>(bf1 + c0);
        float4 b1 = *reinterpret_cast<const float4*>(bf1 + 64 + c0);
        float A0[4] = {b0.x, b0.y, b0.z, b0.w};
        float A1[4] = {b1.x, b1.y, b1.z, b1.w};
        __syncthreads();
        for (int e = tid; e < 2048; e += 256)
            *(reinterpret_cast<float4*>(wbuf) + e) =
                *(reinterpret_cast<const float4*>(Wf1) + e);
        __syncthreads();
        #pragma unroll 4
        for (int k = 0; k < 64; ++k) {
            float a = v[ln][64 + k];
            float4 w0 = *reinterpret_cast<const float4*>(&wbuf[k * 128 + c0]);
            float4 w1 = *reinterpret_cast<const float4*>(&wbuf[k * 128 + 64 + c0]);
            A0[0] += a * w0.x; A0[1] += a * w0.y; A0[2] += a * w0.z; A0[3] += a * w0.w;
            A1[0] += a * w1.x; A1[1] += a * w1.y; A1[2] += a * w1.z; A1[3] += a * w1.w;
        }
        float4 o0 = {fmaxf(A0[0],0.f), fmaxf(A0[1],0.f), fmaxf(A0[2],0.f), fmaxf(A0[3],0.f)};
        float4 o1 = {fmaxf(A1[0],0.f), fmaxf(A1[1],0.f), fmaxf(A1[2],0.f), fmaxf(A1[3],0.f)};
        *reinterpret_cast<float4*>(&tt[ln][c0]) = o0;
        *reinterpret_cast<float4*>(&tt[ln][64 + c0]) = o1;
    }
    // ---- P3: xsl = tt @ Wf2 + bf2, K=128, 64 cols (Wf2 = [128][64]) ----
    {
        float4 b0 = *reinterpret_cast<const float4*>(bf2 + c0);
        float X[4] = {b0.x, b0.y, b0.z, b0.w};
        __syncthreads();
        for (int e = tid; e < 2048; e += 256)
            *(reinterpret_cast<float4*>(wbuf) + e) =
                *(reinterpret_cast<const float4*>(Wf2) + e);
        __syncthreads();
        #pragma unroll 4
        for (int k = 0; k < 128; ++k) {
            float a = tt[ln][k];
            float4 w = *reinterpret_cast<const float4*>(&wbuf[k * 64 + c0]);
            X[0] += a * w.x; X[1] += a * w.y; X[2] += a * w.z; X[3] += a * w.w;
        }
        float4 o = {X[0], X[1], X[2], X[3]};
        *reinterpret_cast<float4*>(&xsl[ln][c0]) = o;
    }
    // ---- P4: [pl|q] = rr @ Wc2 (+ bl2 + xsl on q half), K=128 in 2 chunks ----
    {
        float P0[4] = {0, 0, 0, 0};
        float P1[4] = {0, 0, 0, 0};
        for (int kc = 0; kc < 2; ++kc) {
            __syncthreads();
            for (int e = tid; e < 2048; e += 256)
                *(reinterpret_cast<float4*>(wbuf) + e) =
                    *(reinterpret_cast<const float4*>(Wc2 + kc * 8192) + e);
            __syncthreads();
            #pragma unroll 4
            for (int k = 0; k < 64; ++k) {
                float a = rr[ln][kc * 64 + k];
                float4 w0 = *reinterpret_cast<const float4*>(&wbuf[k * 128 + c0]);
                float4 w1 = *reinterpret_cast<const float4*>(&wbuf[k * 128 + 64 + c0]);
                P0[0] += a * w0.x; P0[1] += a * w0.y; P0[2] += a * w0.z; P0[3] += a * w0.w;
                P1[0] += a * w1.x; P1[1] += a * w1.y; P1[2] += a * w1.z; P1[3] += a * w1.w;
            }
        }
        float4 op = {P0[0], P0[1], P0[2], P0[3]};
        *reinterpret_cast<float4*>(pl + (long)n * FEAT + c0) = op;
        float4 bv = *reinterpret_cast<const float4*>(bl2 + c0);
        float4 oq = {P1[0] + bv.x + xsl[ln][c0 + 0],
                     P1[1] + bv.y + xsl[ln][c0 + 1],
                     P1[2] + bv.z + xsl[ln][c0 + 2],
                     P1[3] + bv.w + xsl[ln][c0 + 3]};
        *reinterpret_cast<float4*>(q + (long)n * FEAT + c0) = oq;
    }
}

// ---------------- gather + Euler epilogue v3 (R26 verbatim) ----------------
__global__ __launch_bounds__(256)
void epi_kernel(const float* __restrict__ pl, const float* __restrict__ q,
                const int* __restrict__ lists, const int* __restrict__ cnt,
                const float* __restrict__ degf, const float* __restrict__ hcur,
                const float* __restrict__ tspan, int step,
                float* __restrict__ hnext) {
    const int tid  = threadIdx.x;
    const int nw   = tid >> 6;            // node within block (one wave per node)
    const int lane = tid & 63;
    const int n  = blockIdx.x * 4 + nw;
    const int eg = lane >> 2;             // neighbor group 0..15
    const int fq = lane & 3;              // feature quad 0..3 (4 float4s each)
    const int m  = cnt[n];
    const int* l = lists + (long)n * CAP;
    float4 a0 = {0,0,0,0}, a1 = {0,0,0,0}, a2 = {0,0,0,0}, a3 = {0,0,0,0};
    for (int e = eg; e < m; e += 16) {
        const float* p = pl + (long)l[e] * FEAT + fq * 16;
        float4 b0 = *reinterpret_cast<const float4*>(p);
        float4 b1 = *reinterpret_cast<const float4*>(p + 4);
        float4 b2 = *reinterpret_cast<const float4*>(p + 8);
        float4 b3 = *reinterpret_cast<const float4*>(p + 12);
        a0.x += b0.x; a0.y += b0.y; a0.z += b0.z; a0.w += b0.w;
        a1.x += b1.x; a1.y += b1.y; a1.z += b1.z; a1.w += b1.w;
        a2.x += b2.x; a2.y += b2.y; a2.z += b2.z; a2.w += b2.w;
        a3.x += b3.x; a3.y += b3.y; a3.z += b3.z; a3.w += b3.w;
    }
    #define RED(A)                                                           \
        (A).x += __shfl_xor((A).x, 4);  (A).y += __shfl_xor((A).y, 4);       \
        (A).z += __shfl_xor((A).z, 4);  (A).w += __shfl_xor((A).w, 4);       \
        (A).x += __shfl_xor((A).x, 8);  (A).y += __shfl_xor((A).y, 8);       \
        (A).z += __shfl_xor((A).z, 8);  (A).w += __shfl_xor((A).w, 8);       \
        (A).x += __shfl_xor((A).x, 16); (A).y += __shfl_xor((A).y, 16);      \
        (A).z += __shfl_xor((A).z, 16); (A).w += __shfl_xor((A).w, 16);      \
        (A).x += __shfl_xor((A).x, 32); (A).y += __shfl_xor((A).y, 32);      \
        (A).z += __shfl_xor((A).z, 32); (A).w += __shfl_xor((A).w, 32);
    RED(a0) RED(a1) RED(a2) RED(a3)
    #undef RED
    if (eg < 4) {                         // writer: float4 idx fq*4 + eg
        float4 a = (eg == 0) ? a0 : (eg == 1) ? a1 : (eg == 2) ? a2 : a3;
        const int f0 = (fq * 4 + eg) * 4;
        const float inv = 1.0f / degf[n];
        const float dt = tspan[step + 1] - tspan[step];
        float4 qv = *reinterpret_cast<const float4*>(q + (long)n * FEAT + f0);
        float4 hv = *reinterpret_cast<const float4*>(hcur + (long)n * FEAT + f0);
        float s0 = qv.x + a.x * inv, s1 = qv.y + a.y * inv;
        float s2 = qv.z + a.z * inv, s3 = qv.w + a.w * inv;
        s0 = fminf(fmaxf(s0, -1000.f), 1000.f); s1 = fminf(fmaxf(s1, -1000.f), 1000.f);
        s2 = fminf(fmaxf(s2, -1000.f), 1000.f); s3 = fminf(fmaxf(s3, -1000.f), 1000.f);
        float4 o = {hv.x + dt * s0, hv.y + dt * s1, hv.z + dt * s2, hv.w + dt * s3};
        *reinterpret_cast<float4*>(hnext + (long)n * FEAT + f0) = o;
    }
}

extern "C" void kernel_launch(void* const* d_in, const int* in_sizes, int n_in,
                              void* d_out, int out_size, void* d_ws, size_t ws_size,
                              hipStream_t stream) {
    const float* tspan = (const float*)d_in[0];
    const float* x     = (const float*)d_in[1];
    const float* adj   = (const float*)d_in[2];
    const float* We1   = (const float*)d_in[3];
    const float* be1   = (const float*)d_in[4];
    const float* We2   = (const float*)d_in[5];
    const float* be2   = (const float*)d_in[6];
    const float* Wf1   = (const float*)d_in[7];
    const float* bf1   = (const float*)d_in[8];
    const float* Wf2   = (const float*)d_in[9];
    const float* bf2   = (const float*)d_in[10];
    const float* Wl1   = (const float*)d_in[11];
    const float* bl1   = (const float*)d_in[12];
    const float* Wr1   = (const float*)d_in[13];
    const float* Wl2   = (const float*)d_in[14];
    const float* bl2   = (const float*)d_in[15];
    const float* Wr2   = (const float*)d_in[16];
    float* out = (float*)d_out;

    // workspace layout (bytes)
    char* ws = (char*)d_ws;
    int*   lists = (int*)  (ws + 0);           // 8000*64*4  = 2,048,000
    int*   cnt   = (int*)  (ws + 2048000);     // 32,000
    float* degf  = (float*)(ws + 2080000);     // 32,000
    float* Ws1   = (float*)(ws + 2112000);     // 65,536
    float* Wc2   = (float*)(ws + 2177536);     // 65,536
    float* pl    = (float*)(ws + 2243072);     // 2,048,000
    float* q     = (float*)(ws + 4291072);     // 2,048,000
    // total 6,339,072 bytes

    front_kernel<<<500, 256, 0, stream>>>(cnt, x, We1, be1, We2, be2, out,
                                          Wl1, Wr1, Wl2, Wr2, Ws1, Wc2);
    build_adj_kernel<<<2048, 256, 0, stream>>>(adj, cnt, lists);

    for (int s = 0; s < 3; ++s) {
        const float* hcur  = out + (long)s       * N_NODES * FEAT;
        float*       hnext = out + (long)(s + 1) * N_NODES * FEAT;
        sageproj_kernel<<<500, 256, 0, stream>>>(hcur, lists, cnt, degf, (s == 0) ? 1 : 0,
                                                 Ws1, bl1, Wc2, bl2,
                                                 Wf1, bf1, Wf2, bf2, pl, q);
        epi_kernel<<<2000, 256, 0, stream>>>(pl, q, lists, cnt, degf, hcur, tspan, s, hnext);
    }
}

// Round 29
// 205.169 us; speedup vs baseline: 1.1180x; 1.0463x over previous
//
#include <hip/hip_runtime.h>

#define N_NODES 8000
#define FEAT 64
#define HID 128
#define LOOKBACK 12
#define CAP 64

// ---------------- front kernel: zero cnt + weight stacking + init encoder ----------------
__global__ __launch_bounds__(256)
void front_kernel(int* __restrict__ cnt,
                  const float* __restrict__ x,
                  const float* __restrict__ We1, const float* __restrict__ be1,
                  const float* __restrict__ We2, const float* __restrict__ be2,
                  float* __restrict__ out0,
                  const float* __restrict__ Wl1, const float* __restrict__ Wr1,
                  const float* __restrict__ Wl2, const float* __restrict__ Wr2,
                  float* __restrict__ Ws1, float* __restrict__ Wc2) {
    __shared__ float sW1T[HID * LOOKBACK];   // [h][l]
    __shared__ float sB1[HID];
    __shared__ float sW2[HID];
    const int tid = threadIdx.x;
    if (tid < 16) cnt[blockIdx.x * 16 + tid] = 0;
    {   // stack weights: first 2*16384 threads write one elem each
        const int gid = blockIdx.x * 256 + tid;
        if (gid < 128 * 128) {              // Ws1[k][j] = [Wl1;Wr1] row-stacked
            int k = gid >> 7, j = gid & 127;
            Ws1[gid] = (k < 64) ? Wl1[k * 128 + j] : Wr1[(k - 64) * 128 + j];
        } else if (gid < 2 * 128 * 128) {   // Wc2[k][j] = [Wl2 | Wr2] col-stacked
            int w = gid - 128 * 128;
            int k = w >> 7, j = w & 127;
            Wc2[w] = (j < 64) ? Wl2[k * 64 + j] : Wr2[k * 64 + (j - 64)];
        }
    }
    for (int e = tid; e < HID * LOOKBACK; e += 256) {
        int l = e / HID, h = e % HID;
        sW1T[h * LOOKBACK + l] = We1[e];
    }
    for (int e = tid; e < HID; e += 256) { sB1[e] = be1[e]; sW2[e] = We2[e]; }
    __syncthreads();
    int g = (blockIdx.x * 256 + tid) * 4;    // 500*256*4 == N*F exactly
    float xv[4][LOOKBACK];
    #pragma unroll
    for (int l = 0; l < LOOKBACK; ++l) {
        float4 v = *reinterpret_cast<const float4*>(x + (long)l * N_NODES * FEAT + g);
        xv[0][l] = v.x; xv[1][l] = v.y; xv[2][l] = v.z; xv[3][l] = v.w;
    }
    float b2 = be2[0];
    float acc[4] = {b2, b2, b2, b2};
    for (int h = 0; h < HID; ++h) {
        float s0 = sB1[h], s1 = s0, s2 = s0, s3 = s0;
        #pragma unroll
        for (int l = 0; l < LOOKBACK; ++l) {
            float w = sW1T[h * LOOKBACK + l];
            s0 += xv[0][l] * w; s1 += xv[1][l] * w;
            s2 += xv[2][l] * w; s3 += xv[3][l] * w;
        }
        float w2 = sW2[h];
        acc[0] += fmaxf(s0, 0.0f) * w2; acc[1] += fmaxf(s1, 0.0f) * w2;
        acc[2] += fmaxf(s2, 0.0f) * w2; acc[3] += fmaxf(s3, 0.0f) * w2;
    }
    float4 o = {acc[0], acc[1], acc[2], acc[3]};
    *reinterpret_cast<float4*>(out0 + g) = o;
}

// ---------------- adjacency extraction: stream-then-drain (R18/R19-verified, ~47us) ----
__global__ __launch_bounds__(256)
void build_adj_kernel(const float* __restrict__ adj, int* __restrict__ cnt,
                      int* __restrict__ lists) {
    const long NQ = (long)N_NODES * N_NODES / 4;     // 16,000,000 float4s
    const long STRIDE = 2048L * 256;                 // 524,288 threads
    const long t = (long)blockIdx.x * 256 + threadIdx.x;

    int lc = 0;
    int e0 = 0, e1 = 0, e2 = 0, e3 = 0, e4 = 0;
    int e5 = 0, e6 = 0, e7 = 0, e8 = 0, e9 = 0;

    #pragma unroll 1
    for (long q = t; q < NQ; q += STRIDE) {
        float4 w = *reinterpret_cast<const float4*>(adj + 4 * q);
        if (w.x != 0.0f || w.y != 0.0f || w.z != 0.0f || w.w != 0.0f) {
            float wv[4] = {w.x, w.y, w.z, w.w};
            #pragma unroll
            for (int c = 0; c < 4; ++c) {
                if (wv[c] != 0.0f) {
                    int e = (int)(q * 4 + c);        // linear elem idx = i*8000+j
                    if      (lc == 0) e0 = e;
                    else if (lc == 1) e1 = e;
                    else if (lc == 2) e2 = e;
                    else if (lc == 3) e3 = e;
                    else if (lc == 4) e4 = e;
                    else if (lc == 5) e5 = e;
                    else if (lc == 6) e6 = e;
                    else if (lc == 7) e7 = e;
                    else if (lc == 8) e8 = e;
                    else if (lc == 9) e9 = e;
                    ++lc;
                }
            }
        }
    }
    #define DRAIN(K, EK)                                                     \
        if (lc > K) {                                                        \
            int ii = (EK) / N_NODES;                                         \
            int jj = (EK) % N_NODES;                                         \
            int p = atomicAdd(&cnt[jj], 1);                                  \
            if (p < CAP) lists[(long)jj * CAP + p] = ii;                     \
        }
    DRAIN(0, e0) DRAIN(1, e1) DRAIN(2, e2) DRAIN(3, e3) DRAIN(4, e4)
    DRAIN(5, e5) DRAIN(6, e6) DRAIN(7, e7) DRAIN(8, e8) DRAIN(9, e9)
    #undef DRAIN
}

// ---------------- fused SAGE1 + proj + selfMLP (+step-0 sort; gather v2) ----------------
// Gather: (node, eg 0..3, fq 0..3) threads; each accumulates edges e==eg (mod 4),
// 4 independent float4 loads per edge; shfl_xor(4,8) tree-reduce (wave-local).
// GEMM phases R19-verbatim.
__global__ __launch_bounds__(256)
void sageproj_kernel(const float* __restrict__ h,
                     int* __restrict__ lists, int* __restrict__ cnt,
                     float* __restrict__ degf, int do_sort,
                     const float* __restrict__ Ws1, const float* __restrict__ bl1,
                     const float* __restrict__ Wc2, const float* __restrict__ bl2,
                     const float* __restrict__ Wf1, const float* __restrict__ bf1,
                     const float* __restrict__ Wf2, const float* __restrict__ bf2,
                     float* __restrict__ pl, float* __restrict__ q) {
    __shared__ float v[16][132];     // [node][k]: k<64 aggr, k>=64 h row
    __shared__ float rr[16][132];    // r1
    __shared__ float tt[16][132];    // t = relu(h@Wf1+bf1)
    __shared__ float xsl[16][68];    // xs
    __shared__ float wbuf[64 * 128]; // 32 KB weight panel chunk
    const int tid = threadIdx.x;
    const int nb = blockIdx.x * 16;
    if (do_sort) {                   // canonicalize own 16 nodes (R16/R19-proven)
        const int wv = tid >> 6, lane = tid & 63;
        #pragma unroll 1
        for (int r = 0; r < 4; ++r) {
            const int n = nb + wv * 4 + r;
            int m = cnt[n]; if (m > CAP) m = CAP;
            int val = (lane < m) ? lists[(long)n * CAP + lane] : 0x7FFFFFFF;
            #pragma unroll
            for (int k = 2; k <= 64; k <<= 1) {
                #pragma unroll
                for (int j = k >> 1; j > 0; j >>= 1) {
                    int other = __shfl_xor(val, j);
                    bool keepMin = (((lane & j) == 0) == ((lane & k) == 0));
                    int mn = val < other ? val : other;
                    int mx = val < other ? other : val;
                    val = keepMin ? mn : mx;
                }
            }
            lists[(long)n * CAP + lane] = val;
            if (lane == 0) { cnt[n] = m; degf[n] = (float)(m > 0 ? m : 1); }
        }
        __syncthreads();
    }
    {   // gather v2: 16 threads/node as (eg 0..3) x (fq 0..3)
        const int ln2 = tid >> 4;
        const int eg  = (tid >> 2) & 3;
        const int fq  = tid & 3;
        const int n2 = nb + ln2;
        const int m = cnt[n2];
        const int* l = lists + (long)n2 * CAP;
        float4 a0 = {0,0,0,0}, a1 = {0,0,0,0}, a2 = {0,0,0,0}, a3 = {0,0,0,0};
        for (int e = eg; e < m; e += 4) {
            const float* p = h + (long)l[e] * FEAT + fq * 16;
            float4 b0 = *reinterpret_cast<const float4*>(p);
            float4 b1 = *reinterpret_cast<const float4*>(p + 4);
            float4 b2 = *reinterpret_cast<const float4*>(p + 8);
            float4 b3 = *reinterpret_cast<const float4*>(p + 12);
            a0.x += b0.x; a0.y += b0.y; a0.z += b0.z; a0.w += b0.w;
            a1.x += b1.x; a1.y += b1.y; a1.z += b1.z; a1.w += b1.w;
            a2.x += b2.x; a2.y += b2.y; a2.z += b2.z; a2.w += b2.w;
            a3.x += b3.x; a3.y += b3.y; a3.z += b3.z; a3.w += b3.w;
        }
        #define RED(A)                                                       \
            (A).x += __shfl_xor((A).x, 4); (A).y += __shfl_xor((A).y, 4);    \
            (A).z += __shfl_xor((A).z, 4); (A).w += __shfl_xor((A).w, 4);    \
            (A).x += __shfl_xor((A).x, 8); (A).y += __shfl_xor((A).y, 8);    \
            (A).z += __shfl_xor((A).z, 8); (A).w += __shfl_xor((A).w, 8);
        RED(a0) RED(a1) RED(a2) RED(a3)
        #undef RED
        const float inv = 1.0f / degf[n2];
        float4 sel = (eg == 0) ? a0 : (eg == 1) ? a1 : (eg == 2) ? a2 : a3;
        float4 av = {sel.x * inv, sel.y * inv, sel.z * inv, sel.w * inv};
        *reinterpret_cast<float4*>(&v[ln2][(fq * 4 + eg) * 4]) = av;
        *reinterpret_cast<float4*>(&v[ln2][64 + (eg * 4 + fq) * 4]) =
            *reinterpret_cast<const float4*>(h + (long)n2 * FEAT + (eg * 4 + fq) * 4);
    }
    const int ln = tid >> 4, jg = tid & 15;
    const int n = nb + ln;
    const int c0 = jg * 4;
    // ---- P1: rr = relu([aggr|h] @ Ws1 + bl1), K=128 in 2 chunks ----
    {
        float4 b0 = *reinterpret_cast<const float4*>(bl1 + c0);
        float4 b1 = *reinterpret_cast<const float4*>(bl1 + 64 + c0);
        float A0[4] = {b0.x, b0.y, b0.z, b0.w};
        float A1[4] = {b1.x, b1.y, b1.z, b1.w};
        for (int kc = 0; kc < 2; ++kc) {
            __syncthreads();                     // prev consumers done / v ready
            for (int e = tid; e < 2048; e += 256)
                *(reinterpret_cast<float4*>(wbuf) + e) =
                    *(reinterpret_cast<const float4*>(Ws1 + kc * 8192) + e);
            __syncthreads();
            #pragma unroll 4
            for (int k = 0; k < 64; ++k) {
                float a = v[ln][kc * 64 + k];
                float4 w0 = *reinterpret_cast<const float4*>(&wbuf[k * 128 + c0]);
                float4 w1 = *reinterpret_cast<const float4*>(&wbuf[k * 128 + 64 + c0]);
                A0[0] += a * w0.x; A0[1] += a * w0.y; A0[2] += a * w0.z; A0[3] += a * w0.w;
                A1[0] += a * w1.x; A1[1] += a * w1.y; A1[2] += a * w1.z; A1[3] += a * w1.w;
            }
        }
        float4 o0 = {fmaxf(A0[0],0.f), fmaxf(A0[1],0.f), fmaxf(A0[2],0.f), fmaxf(A0[3],0.f)};
        float4 o1 = {fmaxf(A1[0],0.f), fmaxf(A1[1],0.f), fmaxf(A1[2],0.f), fmaxf(A1[3],0.f)};
        *reinterpret_cast<float4*>(&rr[ln][c0]) = o0;
        *reinterpret_cast<float4*>(&rr[ln][64 + c0]) = o1;
    }
    // ---- P2: tt = relu(h @ Wf1 + bf1), K=64, one chunk ----
    {
        float4 b0 = *reinterpret_cast<const float4*>(bf1 + c0);
        float4 b1 = *reinterpret_cast<const float4*>(bf1 + 64 + c0);
        float A0[4] = {b0.x, b0.y, b0.z, b0.w};
        float A1[4] = {b1.x, b1.y, b1.z, b1.w};
        __syncthreads();
        for (int e = tid; e < 2048; e += 256)
            *(reinterpret_cast<float4*>(wbuf) + e) =
                *(reinterpret_cast<const float4*>(Wf1) + e);
        __syncthreads();
        #pragma unroll 4
        for (int k = 0; k < 64; ++k) {
            float a = v[ln][64 + k];
            float4 w0 = *reinterpret_cast<const float4*>(&wbuf[k * 128 + c0]);
            float4 w1 = *reinterpret_cast<const float4*>(&wbuf[k * 128 + 64 + c0]);
            A0[0] += a * w0.x; A0[1] += a * w0.y; A0[2] += a * w0.z; A0[3] += a * w0.w;
            A1[0] += a * w1.x; A1[1] += a * w1.y; A1[2] += a * w1.z; A1[3] += a * w1.w;
        }
        float4 o0 = {fmaxf(A0[0],0.f), fmaxf(A0[1],0.f), fmaxf(A0[2],0.f), fmaxf(A0[3],0.f)};
        float4 o1 = {fmaxf(A1[0],0.f), fmaxf(A1[1],0.f), fmaxf(A1[2],0.f), fmaxf(A1[3],0.f)};
        *reinterpret_cast<float4*>(&tt[ln][c0]) = o0;
        *reinterpret_cast<float4*>(&tt[ln][64 + c0]) = o1;
    }
    // ---- P3: xsl = tt @ Wf2 + bf2, K=128, 64 cols (Wf2 = [128][64]) ----
    {
        float4 b0 = *reinterpret_cast<const float4*>(bf2 + c0);
        float X[4] = {b0.x, b0.y, b0.z, b0.w};
        __syncthreads();
        for (int e = tid; e < 2048; e += 256)
            *(reinterpret_cast<float4*>(wbuf) + e) =
                *(reinterpret_cast<const float4*>(Wf2) + e);
        __syncthreads();
        #pragma unroll 4
        for (int k = 0; k < 128; ++k) {
            float a = tt[ln][k];
            float4 w = *reinterpret_cast<const float4*>(&wbuf[k * 64 + c0]);
            X[0] += a * w.x; X[1] += a * w.y; X[2] += a * w.z; X[3] += a * w.w;
        }
        float4 o = {X[0], X[1], X[2], X[3]};
        *reinterpret_cast<float4*>(&xsl[ln][c0]) = o;
    }
    // ---- P4: [pl|q] = rr @ Wc2 (+ bl2 + xsl on q half), K=128 in 2 chunks ----
    {
        float P0[4] = {0, 0, 0, 0};
        float P1[4] = {0, 0, 0, 0};
        for (int kc = 0; kc < 2; ++kc) {
            __syncthreads();
            for (int e = tid; e < 2048; e += 256)
                *(reinterpret_cast<float4*>(wbuf) + e) =
                    *(reinterpret_cast<const float4*>(Wc2 + kc * 8192) + e);
            __syncthreads();
            #pragma unroll 4
            for (int k = 0; k < 64; ++k) {
                float a = rr[ln][kc * 64 + k];
                float4 w0 = *reinterpret_cast<const float4*>(&wbuf[k * 128 + c0]);
                float4 w1 = *reinterpret_cast<const float4*>(&wbuf[k * 128 + 64 + c0]);
                P0[0] += a * w0.x; P0[1] += a * w0.y; P0[2] += a * w0.z; P0[3] += a * w0.w;
                P1[0] += a * w1.x; P1[1] += a * w1.y; P1[2] += a * w1.z; P1[3] += a * w1.w;
            }
        }
        float4 op = {P0[0], P0[1], P0[2], P0[3]};
        *reinterpret_cast<float4*>(pl + (long)n * FEAT + c0) = op;
        float4 bv = *reinterpret_cast<const float4*>(bl2 + c0);
        float4 oq = {P1[0] + bv.x + xsl[ln][c0 + 0],
                     P1[1] + bv.y + xsl[ln][c0 + 1],
                     P1[2] + bv.z + xsl[ln][c0 + 2],
                     P1[3] + bv.w + xsl[ln][c0 + 3]};
        *reinterpret_cast<float4*>(q + (long)n * FEAT + c0) = oq;
    }
}

// ---------------- gather + Euler epilogue v3: 16 neighbor-groups x 4 f-threads ----
__global__ __launch_bounds__(256)
void epi_kernel(const float* __restrict__ pl, const float* __restrict__ q,
                const int* __restrict__ lists, const int* __restrict__ cnt,
                const float* __restrict__ degf, const float* __restrict__ hcur,
                const float* __restrict__ tspan, int step,
                float* __restrict__ hnext) {
    const int tid  = threadIdx.x;
    const int nw   = tid >> 6;            // node within block (one wave per node)
    const int lane = tid & 63;
    const int n  = blockIdx.x * 4 + nw;
    const int eg = lane >> 2;             // neighbor group 0..15
    const int fq = lane & 3;              // feature quad 0..3 (4 float4s each)
    const int m  = cnt[n];
    const int* l = lists + (long)n * CAP;
    float4 a0 = {0,0,0,0}, a1 = {0,0,0,0}, a2 = {0,0,0,0}, a3 = {0,0,0,0};
    for (int e = eg; e < m; e += 16) {
        const float* p = pl + (long)l[e] * FEAT + fq * 16;
        float4 b0 = *reinterpret_cast<const float4*>(p);
        float4 b1 = *reinterpret_cast<const float4*>(p + 4);
        float4 b2 = *reinterpret_cast<const float4*>(p + 8);
        float4 b3 = *reinterpret_cast<const float4*>(p + 12);
        a0.x += b0.x; a0.y += b0.y; a0.z += b0.z; a0.w += b0.w;
        a1.x += b1.x; a1.y += b1.y; a1.z += b1.z; a1.w += b1.w;
        a2.x += b2.x; a2.y += b2.y; a2.z += b2.z; a2.w += b2.w;
        a3.x += b3.x; a3.y += b3.y; a3.z += b3.z; a3.w += b3.w;
    }
    #define RED(A)                                                           \
        (A).x += __shfl_xor((A).x, 4);  (A).y += __shfl_xor((A).y, 4);       \
        (A).z += __shfl_xor((A).z, 4);  (A).w += __shfl_xor((A).w, 4);       \
        (A).x += __shfl_xor((A).x, 8);  (A).y += __shfl_xor((A).y, 8);       \
        (A).z += __shfl_xor((A).z, 8);  (A).w += __shfl_xor((A).w, 8);       \
        (A).x += __shfl_xor((A).x, 16); (A).y += __shfl_xor((A).y, 16);      \
        (A).z += __shfl_xor((A).z, 16); (A).w += __shfl_xor((A).w, 16);      \
        (A).x += __shfl_xor((A).x, 32); (A).y += __shfl_xor((A).y, 32);      \
        (A).z += __shfl_xor((A).z, 32); (A).w += __shfl_xor((A).w, 32);
    RED(a0) RED(a1) RED(a2) RED(a3)
    #undef RED
    if (eg < 4) {                         // writer: float4 idx fq*4 + eg
        float4 a = (eg == 0) ? a0 : (eg == 1) ? a1 : (eg == 2) ? a2 : a3;
        const int f0 = (fq * 4 + eg) * 4;
        const float inv = 1.0f / degf[n];
        const float dt = tspan[step + 1] - tspan[step];
        float4 qv = *reinterpret_cast<const float4*>(q + (long)n * FEAT + f0);
        float4 hv = *reinterpret_cast<const float4*>(hcur + (long)n * FEAT + f0);
        float s0 = qv.x + a.x * inv, s1 = qv.y + a.y * inv;
        float s2 = qv.z + a.z * inv, s3 = qv.w + a.w * inv;
        s0 = fminf(fmaxf(s0, -1000.f), 1000.f); s1 = fminf(fmaxf(s1, -1000.f), 1000.f);
        s2 = fminf(fmaxf(s2, -1000.f), 1000.f); s3 = fminf(fmaxf(s3, -1000.f), 1000.f);
        float4 o = {hv.x + dt * s0, hv.y + dt * s1, hv.z + dt * s2, hv.w + dt * s3};
        *reinterpret_cast<float4*>(hnext + (long)n * FEAT + f0) = o;
    }
}

extern "C" void kernel_launch(void* const* d_in, const int* in_sizes, int n_in,
                              void* d_out, int out_size, void* d_ws, size_t ws_size,
                              hipStream_t stream) {
    const float* tspan = (const float*)d_in[0];
    const float* x     = (const float*)d_in[1];
    const float* adj   = (const float*)d_in[2];
    const float* We1   = (const float*)d_in[3];
    const float* be1   = (const float*)d_in[4];
    const float* We2   = (const float*)d_in[5];
    const float* be2   = (const float*)d_in[6];
    const float* Wf1   = (const float*)d_in[7];
    const float* bf1   = (const float*)d_in[8];
    const float* Wf2   = (const float*)d_in[9];
    const float* bf2   = (const float*)d_in[10];
    const float* Wl1   = (const float*)d_in[11];
    const float* bl1   = (const float*)d_in[12];
    const float* Wr1   = (const float*)d_in[13];
    const float* Wl2   = (const float*)d_in[14];
    const float* bl2   = (const float*)d_in[15];
    const float* Wr2   = (const float*)d_in[16];
    float* out = (float*)d_out;

    // workspace layout (bytes)
    char* ws = (char*)d_ws;
    int*   lists = (int*)  (ws + 0);           // 8000*64*4  = 2,048,000
    int*   cnt   = (int*)  (ws + 2048000);     // 32,000
    float* degf  = (float*)(ws + 2080000);     // 32,000
    float* Ws1   = (float*)(ws + 2112000);     // 65,536
    float* Wc2   = (float*)(ws + 2177536);     // 65,536
    float* pl    = (float*)(ws + 2243072);     // 2,048,000
    float* q     = (float*)(ws + 4291072);     // 2,048,000
    // total 6,339,072 bytes

    front_kernel<<<500, 256, 0, stream>>>(cnt, x, We1, be1, We2, be2, out,
                                          Wl1, Wr1, Wl2, Wr2, Ws1, Wc2);
    build_adj_kernel<<<2048, 256, 0, stream>>>(adj, cnt, lists);

    for (int s = 0; s < 3; ++s) {
        const float* hcur  = out + (long)s       * N_NODES * FEAT;
        float*       hnext = out + (long)(s + 1) * N_NODES * FEAT;
        sageproj_kernel<<<500, 256, 0, stream>>>(hcur, lists, cnt, degf, (s == 0) ? 1 : 0,
                                                 Ws1, bl1, Wc2, bl2,
                                                 Wf1, bf1, Wf2, bf2, pl, q);
        epi_kernel<<<2000, 256, 0, stream>>>(pl, q, lists, cnt, degf, hcur, tspan, s, hnext);
    }
}